// Round 1
// baseline (904.610 us; speedup 1.0000x reference)
//
#include <hip/hip_runtime.h>
#include <hip/hip_bf16.h>

#define NN 50000
#define NE 800000
#define FD 256
#define LD 128
#define BN_EPS 1e-5f

// ---------------- CSR build ----------------

__global__ __launch_bounds__(256) void k_count(const int* __restrict__ dst,
                                               int* __restrict__ cnt) {
  int i = blockIdx.x * blockDim.x + threadIdx.x;
  if (i < NE) atomicAdd(&cnt[dst[i]], 1);
}

// single-block exclusive scan of cnt[0..NN) -> row_ptr[0..NN]
__global__ __launch_bounds__(1024) void k_scan(const int* __restrict__ cnt,
                                               int* __restrict__ row_ptr) {
  __shared__ int wsum[16];
  __shared__ int s_carry;
  int t = threadIdx.x;
  int lane = t & 63, wid = t >> 6;
  if (t == 0) s_carry = 0;
  __syncthreads();
  for (int base = 0; base < NN; base += 1024) {
    int v = (base + t < NN) ? cnt[base + t] : 0;
    int x = v;
#pragma unroll
    for (int off = 1; off < 64; off <<= 1) {
      int y = __shfl_up(x, off, 64);
      if (lane >= off) x += y;
    }
    if (lane == 63) wsum[wid] = x;
    __syncthreads();
    if (wid == 0 && lane < 16) {
      int w = wsum[lane];
#pragma unroll
      for (int off = 1; off < 16; off <<= 1) {
        int y = __shfl_up(w, off, 64);
        if (lane >= off) w += y;
      }
      wsum[lane] = w;
    }
    __syncthreads();
    int waveoff = (wid > 0) ? wsum[wid - 1] : 0;
    int carry = s_carry;
    int incl = carry + waveoff + x;
    if (base + t < NN) row_ptr[base + t] = incl - v;  // exclusive
    __syncthreads();
    if (t == 1023) s_carry = incl;
    __syncthreads();
  }
  if (t == 0) row_ptr[NN] = s_carry;
}

__global__ __launch_bounds__(256) void k_dinv(const int* __restrict__ cnt,
                                              float* __restrict__ dinv) {
  int i = blockIdx.x * blockDim.x + threadIdx.x;
  if (i < NN) dinv[i] = rsqrtf(1.0f + (float)cnt[i]);  // deg = 1 (self) + in-edges
}

__global__ __launch_bounds__(256) void k_fill(const int* __restrict__ src,
                                              const int* __restrict__ dst,
                                              const int* __restrict__ row_ptr,
                                              int* __restrict__ cursor,
                                              int* __restrict__ col) {
  int i = blockIdx.x * blockDim.x + threadIdx.x;
  if (i < NE) {
    int d = dst[i];
    int p = atomicAdd(&cursor[d], 1);
    col[row_ptr[d] + p] = src[i];
  }
}

// ---------------- GEMM (fp32 vector) ----------------
// C[M x Nout] = rowscale ? diag(rowscale) * (f(A) @ B) : f(A) @ B   (+ colbias)
// f(A) = bn_scale ? relu(A * bn_scale[col] + bn_shift[col]) : A   (per A-column)
// K fixed = 256 = FD. Tile: BM=BN=64, BK=16, 256 threads, 4x4 microtile.
__global__ __launch_bounds__(256) void k_gemm(
    const float* __restrict__ A, const float* __restrict__ B,
    float* __restrict__ C, int M, int Nout,
    const float* __restrict__ row_scale,
    const float* __restrict__ bn_scale, const float* __restrict__ bn_shift,
    const float* __restrict__ col_bias) {
  __shared__ float As[16][68];  // [k][m], pad 64->68 keeps 16B align, 2-way max
  __shared__ float Bs[16][68];  // [k][n]
  const int bm = blockIdx.x * 64;
  const int bn = blockIdx.y * 64;
  const int tid = threadIdx.x;
  const int tx = tid & 15, ty = tid >> 4;
  const int lk = tid & 15;   // A-load col within tile
  const int lr0 = tid >> 4;  // A-load row base
  const int ln = tid & 63;   // B-load col
  const int lk0 = tid >> 6;  // B-load row base
  float acc[4][4] = {};
  for (int k0 = 0; k0 < FD; k0 += 16) {
    float bnsc = 0.f, bnsh = 0.f;
    if (bn_scale) { bnsc = bn_scale[k0 + lk]; bnsh = bn_shift[k0 + lk]; }
#pragma unroll
    for (int i = 0; i < 4; ++i) {
      int r = lr0 + 16 * i;
      int grow = bm + r;
      float v = 0.f;
      if (grow < M) {
        v = A[(size_t)grow * FD + k0 + lk];
        if (bn_scale) v = fmaxf(fmaf(v, bnsc, bnsh), 0.f);
        if (row_scale) v *= row_scale[grow];
      }
      As[lk][r] = v;
    }
#pragma unroll
    for (int i = 0; i < 4; ++i) {
      int k = lk0 + 4 * i;
      Bs[k][ln] = B[(size_t)(k0 + k) * Nout + bn + ln];
    }
    __syncthreads();
#pragma unroll
    for (int k = 0; k < 16; ++k) {
      float a[4], b[4];
#pragma unroll
      for (int i = 0; i < 4; ++i) a[i] = As[k][ty * 4 + i];
#pragma unroll
      for (int j = 0; j < 4; ++j) b[j] = Bs[k][tx * 4 + j];
#pragma unroll
      for (int i = 0; i < 4; ++i)
#pragma unroll
        for (int j = 0; j < 4; ++j) acc[i][j] = fmaf(a[i], b[j], acc[i][j]);
    }
    __syncthreads();
  }
#pragma unroll
  for (int i = 0; i < 4; ++i) {
    int r = bm + ty * 4 + i;
    if (r >= M) continue;
    int c0 = bn + tx * 4;
    float4 v;
    v.x = acc[i][0]; v.y = acc[i][1]; v.z = acc[i][2]; v.w = acc[i][3];
    if (col_bias) {
      v.x += col_bias[c0 + 0]; v.y += col_bias[c0 + 1];
      v.z += col_bias[c0 + 2]; v.w += col_bias[c0 + 3];
    }
    *(float4*)&C[(size_t)r * Nout + c0] = v;
  }
}

// ---------------- SpMM: out[dst] = dinv[dst] * (g[dst] + sum_in g[src]) -----
// one wave per dst row; lane holds 4 consecutive floats (float4)
__global__ __launch_bounds__(256) void k_spmm(const float4* __restrict__ g4,
                                              const int* __restrict__ row_ptr,
                                              const int* __restrict__ col,
                                              const float* __restrict__ dinv,
                                              float4* __restrict__ out4) {
  int wid = threadIdx.x >> 6, lane = threadIdx.x & 63;
  int dst = blockIdx.x * 4 + wid;
  if (dst >= NN) return;
  int s = row_ptr[dst], e = row_ptr[dst + 1];
  float4 acc = g4[(size_t)dst * 64 + lane];  // self loop
  for (int base = s; base < e; base += 64) {
    int n = e - base;
    if (n > 64) n = 64;
    int c = (base + lane < e) ? col[base + lane] : 0;
    for (int i = 0; i < n; ++i) {
      int srcn = __shfl(c, i, 64);
      float4 v = g4[(size_t)srcn * 64 + lane];
      acc.x += v.x; acc.y += v.y; acc.z += v.z; acc.w += v.w;
    }
  }
  float dv = dinv[dst];
  float4 o;
  o.x = acc.x * dv; o.y = acc.y * dv; o.z = acc.z * dv; o.w = acc.w * dv;
  out4[(size_t)dst * 64 + lane] = o;
}

// ---------------- BatchNorm statistics ----------------
__global__ __launch_bounds__(256) void k_bnstats(const float* __restrict__ h,
                                                 float* __restrict__ stats) {
  int t = threadIdx.x;  // feature
  int r0 = blockIdx.x * 128;
  int r1 = r0 + 128;
  if (r1 > NN) r1 = NN;
  float s = 0.f, s2 = 0.f;
  for (int r = r0; r < r1; ++r) {
    float v = h[(size_t)r * FD + t];
    s += v;
    s2 = fmaf(v, v, s2);
  }
  atomicAdd(&stats[t], s);
  atomicAdd(&stats[FD + t], s2);
}

__global__ __launch_bounds__(256) void k_bnfinal(const float* __restrict__ stats,
                                                 const float* __restrict__ gamma,
                                                 const float* __restrict__ beta,
                                                 float* __restrict__ bnsc,
                                                 float* __restrict__ bnsh) {
  int t = threadIdx.x;
  float mean = stats[t] * (1.0f / NN);
  float var = stats[FD + t] * (1.0f / NN) - mean * mean;
  float rs = rsqrtf(var + BN_EPS);
  float sc = gamma[t] * rs;
  bnsc[t] = sc;
  bnsh[t] = beta[t] - mean * sc;
}

// ---------------- launch ----------------
extern "C" void kernel_launch(void* const* d_in, const int* in_sizes, int n_in,
                              void* d_out, int out_size, void* d_ws, size_t ws_size,
                              hipStream_t stream) {
  const float* x = (const float*)d_in[0];
  const int* ei = (const int*)d_in[1];
  const int* esrc = ei;        // edge_index[0]
  const int* edst = ei + NE;   // edge_index[1]
  const float* W0 = (const float*)d_in[2];
  // b0 (d_in[3]) / b1 (d_in[7]) are absorbed by BN mean-subtraction -> skipped
  const float* gamma0 = (const float*)d_in[4];
  const float* beta0 = (const float*)d_in[5];
  const float* W1 = (const float*)d_in[6];
  const float* gamma1 = (const float*)d_in[8];
  const float* beta1 = (const float*)d_in[9];
  const float* W_mu = (const float*)d_in[10];
  const float* b_mu = (const float*)d_in[11];
  const float* W_lv = (const float*)d_in[12];
  const float* b_lv = (const float*)d_in[13];
  float* out = (float*)d_out;

  // workspace carve (~107 MB)
  float* bufA = (float*)d_ws;                       // NN*FD
  float* bufB = bufA + (size_t)NN * FD;             // NN*FD
  float* dinv = bufB + (size_t)NN * FD;             // NN
  float* stats = dinv + NN;                         // 2*FD
  float* bnsc0 = stats + 2 * FD;
  float* bnsh0 = bnsc0 + FD;
  float* bnsc1 = bnsh0 + FD;
  float* bnsh1 = bnsc1 + FD;
  int* cnt = (int*)(bnsh1 + FD);                    // NN
  int* row_ptr = cnt + NN;                          // NN+1
  int* cursor = row_ptr + NN + 1;                   // NN
  int* col = cursor + NN;                           // NE

  hipMemsetAsync(cnt, 0, NN * sizeof(int), stream);
  hipMemsetAsync(cursor, 0, NN * sizeof(int), stream);
  k_count<<<(NE + 255) / 256, 256, 0, stream>>>(edst, cnt);
  k_scan<<<1, 1024, 0, stream>>>(cnt, row_ptr);
  k_dinv<<<(NN + 255) / 256, 256, 0, stream>>>(cnt, dinv);
  k_fill<<<(NE + 255) / 256, 256, 0, stream>>>(esrc, edst, row_ptr, cursor, col);

  dim3 g256((NN + 63) / 64, FD / 64);
  dim3 g128((NN + 63) / 64, LD / 64);

  // layer 0: g0 = diag(dinv) * (x @ W0)
  k_gemm<<<g256, 256, 0, stream>>>(x, W0, bufA, NN, FD, dinv, nullptr, nullptr, nullptr);
  k_spmm<<<(NN + 3) / 4, 256, 0, stream>>>((const float4*)bufA, row_ptr, col, dinv,
                                           (float4*)bufB);
  hipMemsetAsync(stats, 0, 2 * FD * sizeof(float), stream);
  k_bnstats<<<(NN + 127) / 128, 256, 0, stream>>>(bufB, stats);
  k_bnfinal<<<1, FD, 0, stream>>>(stats, gamma0, beta0, bnsc0, bnsh0);

  // layer 1: g1 = diag(dinv) * (relu(bn(agg0)) @ W1)   [bn+relu fused in A-load]
  k_gemm<<<g256, 256, 0, stream>>>(bufB, W1, bufA, NN, FD, dinv, bnsc0, bnsh0, nullptr);
  k_spmm<<<(NN + 3) / 4, 256, 0, stream>>>((const float4*)bufA, row_ptr, col, dinv,
                                           (float4*)bufB);
  hipMemsetAsync(stats, 0, 2 * FD * sizeof(float), stream);
  k_bnstats<<<(NN + 127) / 128, 256, 0, stream>>>(bufB, stats);
  k_bnfinal<<<1, FD, 0, stream>>>(stats, gamma1, beta1, bnsc1, bnsh1);

  // heads: mu / logvar from h2 = relu(bn(agg1)) (fused in A-load)
  k_gemm<<<g128, 256, 0, stream>>>(bufB, W_mu, out, NN, LD, nullptr, bnsc1, bnsh1, b_mu);
  k_gemm<<<g128, 256, 0, stream>>>(bufB, W_lv, out + (size_t)NN * LD, NN, LD, nullptr,
                                   bnsc1, bnsh1, b_lv);
}

// Round 2
// 565.597 us; speedup vs baseline: 1.5994x; 1.5994x over previous
//
#include <hip/hip_runtime.h>
#include <hip/hip_bf16.h>

#define NN 50000
#define NE 800000
#define FD 256
#define LD 128
#define BN_EPS 1e-5f

typedef __bf16 bf16_t;
typedef bf16_t bf16x8 __attribute__((ext_vector_type(8)));
typedef bf16_t bf16x4 __attribute__((ext_vector_type(4)));
typedef float f32x4 __attribute__((ext_vector_type(4)));

// ---------------- CSR build ----------------

__global__ __launch_bounds__(256) void k_count(const int* __restrict__ dst,
                                               int* __restrict__ cnt) {
  int i = blockIdx.x * blockDim.x + threadIdx.x;
  if (i < NE) atomicAdd(&cnt[dst[i]], 1);
}

// hierarchical exclusive scan: A (per-block), B (scan partials), C (add offsets)
__global__ __launch_bounds__(256) void k_scanA(const int* __restrict__ cnt,
                                               int* __restrict__ row_ptr,
                                               int* __restrict__ partials) {
  __shared__ int ws[4];
  int b = blockIdx.x, t = threadIdx.x;
  int base = b * 1024 + t * 4;
  int vals[4];
#pragma unroll
  for (int j = 0; j < 4; ++j) vals[j] = (base + j < NN) ? cnt[base + j] : 0;
  int tsum = vals[0] + vals[1] + vals[2] + vals[3];
  int lane = t & 63, wid = t >> 6;
  int x = tsum;
#pragma unroll
  for (int off = 1; off < 64; off <<= 1) {
    int y = __shfl_up(x, off, 64);
    if (lane >= off) x += y;
  }
  if (lane == 63) ws[wid] = x;
  __syncthreads();
  int woff = 0;
  for (int w = 0; w < wid; ++w) woff += ws[w];
  int run = woff + x - tsum;  // exclusive prefix of this thread within block
#pragma unroll
  for (int j = 0; j < 4; ++j) {
    if (base + j < NN) row_ptr[base + j] = run;
    run += vals[j];
  }
  if (t == 255) partials[b] = woff + x;
}

__global__ void k_scanB(int* __restrict__ partials, int* __restrict__ row_ptr,
                        int nblk) {
  int lane = threadIdx.x;
  int v = (lane < nblk) ? partials[lane] : 0;
  int x = v;
#pragma unroll
  for (int off = 1; off < 64; off <<= 1) {
    int y = __shfl_up(x, off, 64);
    if (lane >= off) x += y;
  }
  if (lane < nblk) partials[lane] = x - v;  // exclusive
  if (lane == 0) row_ptr[NN] = NE;
}

__global__ __launch_bounds__(256) void k_scanC(int* __restrict__ row_ptr,
                                               const int* __restrict__ partials) {
  int b = blockIdx.x;
  int off = partials[b];
  int base = b * 1024 + threadIdx.x * 4;
#pragma unroll
  for (int j = 0; j < 4; ++j)
    if (base + j < NN) row_ptr[base + j] += off;
}

__global__ __launch_bounds__(256) void k_dinv(const int* __restrict__ cnt,
                                              float* __restrict__ dinv) {
  int i = blockIdx.x * blockDim.x + threadIdx.x;
  if (i < NN) dinv[i] = rsqrtf(1.0f + (float)cnt[i]);
}

__global__ __launch_bounds__(256) void k_fill(const int* __restrict__ src,
                                              const int* __restrict__ dst,
                                              const int* __restrict__ row_ptr,
                                              int* __restrict__ cursor,
                                              int* __restrict__ col) {
  int i = blockIdx.x * blockDim.x + threadIdx.x;
  if (i < NE) {
    int d = dst[i];
    int p = atomicAdd(&cursor[d], 1);
    col[row_ptr[d] + p] = src[i];
  }
}

// ---------------- weight convert: fp32 [K][N] -> bf16 [N][K], heads fused ----
__global__ __launch_bounds__(256) void k_convw(
    const float* __restrict__ W0, const float* __restrict__ W1,
    const float* __restrict__ Wmu, const float* __restrict__ bmu,
    const float* __restrict__ Wlv, const float* __restrict__ blv,
    bf16_t* __restrict__ W0t, bf16_t* __restrict__ W1t,
    bf16_t* __restrict__ Wht, float* __restrict__ biash) {
  int k = blockIdx.x, n = threadIdx.x;  // 256 x 256
  W0t[n * 256 + k] = (bf16_t)W0[k * 256 + n];
  W1t[n * 256 + k] = (bf16_t)W1[k * 256 + n];
  float wh = (n < 128) ? Wmu[k * 128 + n] : Wlv[k * 128 + (n - 128)];
  Wht[n * 256 + k] = (bf16_t)wh;
  if (k == 0) biash[n] = (n < 128) ? bmu[n] : blv[n - 128];
}

// ---------------- MFMA GEMM ----------------
// C[M x 256] = f(A) @ Bt^T ; f = optional bn(scale,shift)+relu per A-col.
// epilogue: optional row_scale (dinv); optional col_bias; writes bf16 Cb OR
// fp32 Cf (split=1: cols 0-127 -> Cf (mu), 128-255 -> Cf + M*128 (logvar)).
// K = 256 fixed. Tile BM=BN=128, BK=32, 256 threads (4 waves, 2x2 of 64x64).
#define LDKP 40  // padded LDS k-stride (elems): 80B rows -> <=2-way conflicts

__global__ __launch_bounds__(256) void k_mgemm(
    const float* __restrict__ A, const bf16_t* __restrict__ Bt,
    bf16_t* __restrict__ Cb, float* __restrict__ Cf, int M,
    const float* __restrict__ bn_scale, const float* __restrict__ bn_shift,
    const float* __restrict__ row_scale, const float* __restrict__ col_bias,
    int split) {
  __shared__ bf16_t As[128 * LDKP];
  __shared__ bf16_t Bs[128 * LDKP];
  const int tid = threadIdx.x;
  const int bm = blockIdx.x * 128;
  const int bn = blockIdx.y * 128;
  const int wave = tid >> 6, lane = tid & 63;
  const int wm = (wave >> 1) * 64, wn = (wave & 1) * 64;
  const int lm = lane & 15, lq = lane >> 4;
  const int ar = tid >> 3;          // A stage: rows ar + 32*i
  const int ak = (tid & 7) * 4;     // A stage: k offset (floats)
  const int br = tid >> 2;          // B stage: rows br + 64*i
  const int bk = (tid & 3) * 8;     // B stage: k offset (bf16)
  f32x4 acc[4][4] = {};

  for (int k0 = 0; k0 < 256; k0 += 32) {
    float4 sc, sh;
    if (bn_scale) {
      sc = *(const float4*)&bn_scale[k0 + ak];
      sh = *(const float4*)&bn_shift[k0 + ak];
    }
#pragma unroll
    for (int i = 0; i < 4; ++i) {
      int r = ar + 32 * i;
      int grow = bm + r;
      float4 v = make_float4(0.f, 0.f, 0.f, 0.f);
      if (grow < M) v = *(const float4*)&A[(size_t)grow * 256 + k0 + ak];
      if (bn_scale) {
        v.x = fmaxf(fmaf(v.x, sc.x, sh.x), 0.f);
        v.y = fmaxf(fmaf(v.y, sc.y, sh.y), 0.f);
        v.z = fmaxf(fmaf(v.z, sc.z, sh.z), 0.f);
        v.w = fmaxf(fmaf(v.w, sc.w, sh.w), 0.f);
      }
      bf16x4 b4 = {(bf16_t)v.x, (bf16_t)v.y, (bf16_t)v.z, (bf16_t)v.w};
      *(bf16x4*)&As[r * LDKP + ak] = b4;
    }
#pragma unroll
    for (int i = 0; i < 2; ++i) {
      int n = br + 64 * i;
      bf16x8 b8 = *(const bf16x8*)&Bt[(size_t)(bn + n) * 256 + k0 + bk];
      *(bf16x8*)&Bs[n * LDKP + bk] = b8;
    }
    __syncthreads();
    bf16x8 af[4], bfr[4];
#pragma unroll
    for (int t = 0; t < 4; ++t)
      af[t] = *(const bf16x8*)&As[(wm + t * 16 + lm) * LDKP + lq * 8];
#pragma unroll
    for (int t = 0; t < 4; ++t)
      bfr[t] = *(const bf16x8*)&Bs[(wn + t * 16 + lm) * LDKP + lq * 8];
#pragma unroll
    for (int i = 0; i < 4; ++i)
#pragma unroll
      for (int j = 0; j < 4; ++j)
        acc[i][j] = __builtin_amdgcn_mfma_f32_16x16x32_bf16(af[i], bfr[j],
                                                            acc[i][j], 0, 0, 0);
    __syncthreads();
  }
  // epilogue: D row = wm+i*16+lq*4+r, col = wn+j*16+lm  [m89-verified layout]
#pragma unroll
  for (int i = 0; i < 4; ++i) {
#pragma unroll
    for (int r = 0; r < 4; ++r) {
      int grow = bm + wm + i * 16 + lq * 4 + r;
      if (grow >= M) continue;
      float rs = row_scale ? row_scale[grow] : 1.0f;
#pragma unroll
      for (int j = 0; j < 4; ++j) {
        int gcol = bn + wn + j * 16 + lm;
        float v = acc[i][j][r] * rs;
        if (col_bias) v += col_bias[gcol];
        if (Cb) {
          Cb[(size_t)grow * 256 + gcol] = (bf16_t)v;
        } else if (!split) {
          Cf[(size_t)grow * 256 + gcol] = v;
        } else {
          if (gcol < 128)
            Cf[(size_t)grow * 128 + gcol] = v;
          else
            Cf[(size_t)(M + grow) * 128 + (gcol - 128)] = v;
        }
      }
    }
  }
}

// ---------------- SpMM: agg[dst] = dinv[dst]*(g[dst] + sum g[src]) ---------
// g is bf16 [NN][256]; one wave per dst row; lane owns 4 features (8B).
__global__ __launch_bounds__(256) void k_spmm(const bf16_t* __restrict__ g,
                                              const int* __restrict__ row_ptr,
                                              const int* __restrict__ col,
                                              const float* __restrict__ dinv,
                                              float* __restrict__ out) {
  int wid = threadIdx.x >> 6, lane = threadIdx.x & 63;
  int dst = blockIdx.x * 4 + wid;
  if (dst >= NN) return;
  int s = row_ptr[dst], e = row_ptr[dst + 1];
  bf16x4 sv = *(const bf16x4*)&g[(size_t)dst * 256 + lane * 4];
  float ax = (float)sv[0], ay = (float)sv[1], az = (float)sv[2], aw = (float)sv[3];
  for (int b0 = s; b0 < e; b0 += 64) {
    int n = e - b0;
    if (n > 64) n = 64;
    int c = (b0 + lane < e) ? col[b0 + lane] : 0;
    int i = 0;
    for (; i + 4 <= n; i += 4) {
      int s0 = __shfl(c, i, 64), s1 = __shfl(c, i + 1, 64);
      int s2 = __shfl(c, i + 2, 64), s3 = __shfl(c, i + 3, 64);
      bf16x4 v0 = *(const bf16x4*)&g[(size_t)s0 * 256 + lane * 4];
      bf16x4 v1 = *(const bf16x4*)&g[(size_t)s1 * 256 + lane * 4];
      bf16x4 v2 = *(const bf16x4*)&g[(size_t)s2 * 256 + lane * 4];
      bf16x4 v3 = *(const bf16x4*)&g[(size_t)s3 * 256 + lane * 4];
      ax += (float)v0[0] + (float)v1[0] + (float)v2[0] + (float)v3[0];
      ay += (float)v0[1] + (float)v1[1] + (float)v2[1] + (float)v3[1];
      az += (float)v0[2] + (float)v1[2] + (float)v2[2] + (float)v3[2];
      aw += (float)v0[3] + (float)v1[3] + (float)v2[3] + (float)v3[3];
    }
    for (; i < n; ++i) {
      int sn = __shfl(c, i, 64);
      bf16x4 v = *(const bf16x4*)&g[(size_t)sn * 256 + lane * 4];
      ax += (float)v[0]; ay += (float)v[1]; az += (float)v[2]; aw += (float)v[3];
    }
  }
  float dv = dinv[dst];
  float4 o;
  o.x = ax * dv; o.y = ay * dv; o.z = az * dv; o.w = aw * dv;
  *(float4*)&out[(size_t)dst * 256 + lane * 4] = o;
}

// ---------------- BatchNorm statistics ----------------
__global__ __launch_bounds__(256) void k_bnstats(const float* __restrict__ h,
                                                 float* __restrict__ stats) {
  int t = threadIdx.x;
  int r0 = blockIdx.x * 128;
  int r1 = r0 + 128;
  if (r1 > NN) r1 = NN;
  float s = 0.f, s2 = 0.f;
  for (int r = r0; r < r1; ++r) {
    float v = h[(size_t)r * FD + t];
    s += v;
    s2 = fmaf(v, v, s2);
  }
  atomicAdd(&stats[t], s);
  atomicAdd(&stats[FD + t], s2);
}

__global__ __launch_bounds__(256) void k_bnfinal(const float* __restrict__ stats,
                                                 const float* __restrict__ gamma,
                                                 const float* __restrict__ beta,
                                                 float* __restrict__ bnsc,
                                                 float* __restrict__ bnsh) {
  int t = threadIdx.x;
  float mean = stats[t] * (1.0f / NN);
  float var = stats[FD + t] * (1.0f / NN) - mean * mean;
  float rs = rsqrtf(var + BN_EPS);
  float sc = gamma[t] * rs;
  bnsc[t] = sc;
  bnsh[t] = beta[t] - mean * sc;
}

// ---------------- launch ----------------
extern "C" void kernel_launch(void* const* d_in, const int* in_sizes, int n_in,
                              void* d_out, int out_size, void* d_ws, size_t ws_size,
                              hipStream_t stream) {
  const float* x = (const float*)d_in[0];
  const int* ei = (const int*)d_in[1];
  const int* esrc = ei;
  const int* edst = ei + NE;
  const float* W0 = (const float*)d_in[2];
  const float* gamma0 = (const float*)d_in[4];
  const float* beta0 = (const float*)d_in[5];
  const float* W1 = (const float*)d_in[6];
  const float* gamma1 = (const float*)d_in[8];
  const float* beta1 = (const float*)d_in[9];
  const float* W_mu = (const float*)d_in[10];
  const float* b_mu = (const float*)d_in[11];
  const float* W_lv = (const float*)d_in[12];
  const float* b_lv = (const float*)d_in[13];
  float* out = (float*)d_out;

  // workspace carve (all 16B-aligned)
  float* agg = (float*)d_ws;                      // NN*256 fp32
  bf16_t* g16 = (bf16_t*)(agg + (size_t)NN * 256);  // NN*256 bf16
  float* dinv = (float*)(g16 + (size_t)NN * 256);   // NN
  float* stats = dinv + NN;                       // 2*FD
  float* bnsc0 = stats + 2 * FD;
  float* bnsh0 = bnsc0 + FD;
  float* bnsc1 = bnsh0 + FD;
  float* bnsh1 = bnsc1 + FD;
  float* biash = bnsh1 + FD;                      // 256
  bf16_t* W0t = (bf16_t*)(biash + 256);           // 64K bf16
  bf16_t* W1t = W0t + 256 * 256;
  bf16_t* Wht = W1t + 256 * 256;
  int* cnt = (int*)(Wht + 256 * 256);             // NN
  int* row_ptr = cnt + NN;                        // NN+4 (padded)
  int* cursor = row_ptr + NN + 4;                 // NN
  int* col = cursor + NN;                         // NE
  int* partials = col + NE;                       // 64

  const int SCAN_BLKS = (NN + 1023) / 1024;  // 49

  hipMemsetAsync(cnt, 0, NN * sizeof(int), stream);
  hipMemsetAsync(cursor, 0, NN * sizeof(int), stream);
  k_count<<<(NE + 255) / 256, 256, 0, stream>>>(edst, cnt);
  k_scanA<<<SCAN_BLKS, 256, 0, stream>>>(cnt, row_ptr, partials);
  k_scanB<<<1, 64, 0, stream>>>(partials, row_ptr, SCAN_BLKS);
  k_scanC<<<SCAN_BLKS, 256, 0, stream>>>(row_ptr, partials);
  k_dinv<<<(NN + 255) / 256, 256, 0, stream>>>(cnt, dinv);
  k_fill<<<(NE + 255) / 256, 256, 0, stream>>>(esrc, edst, row_ptr, cursor, col);
  k_convw<<<256, 256, 0, stream>>>(W0, W1, W_mu, b_mu, W_lv, b_lv, W0t, W1t, Wht, biash);

  dim3 gg((NN + 127) / 128, 2);

  // layer 0: g0 = diag(dinv)*(x @ W0)   [bf16 out]
  k_mgemm<<<gg, 256, 0, stream>>>(x, W0t, g16, nullptr, NN, nullptr, nullptr,
                                  dinv, nullptr, 0);
  k_spmm<<<(NN + 3) / 4, 256, 0, stream>>>(g16, row_ptr, col, dinv, agg);
  hipMemsetAsync(stats, 0, 2 * FD * sizeof(float), stream);
  k_bnstats<<<(NN + 127) / 128, 256, 0, stream>>>(agg, stats);
  k_bnfinal<<<1, FD, 0, stream>>>(stats, gamma0, beta0, bnsc0, bnsh0);

  // layer 1: g1 = diag(dinv)*(relu(bn(agg)) @ W1)
  k_mgemm<<<gg, 256, 0, stream>>>(agg, W1t, g16, nullptr, NN, bnsc0, bnsh0,
                                  dinv, nullptr, 0);
  k_spmm<<<(NN + 3) / 4, 256, 0, stream>>>(g16, row_ptr, col, dinv, agg);
  hipMemsetAsync(stats, 0, 2 * FD * sizeof(float), stream);
  k_bnstats<<<(NN + 127) / 128, 256, 0, stream>>>(agg, stats);
  k_bnfinal<<<1, FD, 0, stream>>>(stats, gamma1, beta1, bnsc1, bnsh1);

  // heads (fused mu|logvar): out = relu(bn(agg)) @ [W_mu|W_lv] + [b_mu|b_lv]
  k_mgemm<<<gg, 256, 0, stream>>>(agg, Wht, nullptr, out, NN, bnsc1, bnsh1,
                                  nullptr, biash, 1);
}

// Round 3
// 531.194 us; speedup vs baseline: 1.7030x; 1.0648x over previous
//
#include <hip/hip_runtime.h>
#include <hip/hip_bf16.h>

#define NN 50000
#define NE 800000
#define FD 256
#define LD 128
#define BN_EPS 1e-5f

typedef __bf16 bf16_t;
typedef bf16_t bf16x8 __attribute__((ext_vector_type(8)));
typedef bf16_t bf16x4 __attribute__((ext_vector_type(4)));
typedef float f32x4 __attribute__((ext_vector_type(4)));

// ---------------- CSR build ----------------

__global__ __launch_bounds__(256) void k_count(const int* __restrict__ dst,
                                               int* __restrict__ cnt) {
  int i = blockIdx.x * blockDim.x + threadIdx.x;
  if (i < NE) atomicAdd(&cnt[dst[i]], 1);
}

__global__ __launch_bounds__(256) void k_scanA(const int* __restrict__ cnt,
                                               int* __restrict__ row_ptr,
                                               int* __restrict__ partials) {
  __shared__ int ws[4];
  int b = blockIdx.x, t = threadIdx.x;
  int base = b * 1024 + t * 4;
  int vals[4];
#pragma unroll
  for (int j = 0; j < 4; ++j) vals[j] = (base + j < NN) ? cnt[base + j] : 0;
  int tsum = vals[0] + vals[1] + vals[2] + vals[3];
  int lane = t & 63, wid = t >> 6;
  int x = tsum;
#pragma unroll
  for (int off = 1; off < 64; off <<= 1) {
    int y = __shfl_up(x, off, 64);
    if (lane >= off) x += y;
  }
  if (lane == 63) ws[wid] = x;
  __syncthreads();
  int woff = 0;
  for (int w = 0; w < wid; ++w) woff += ws[w];
  int run = woff + x - tsum;
#pragma unroll
  for (int j = 0; j < 4; ++j) {
    if (base + j < NN) row_ptr[base + j] = run;
    run += vals[j];
  }
  if (t == 255) partials[b] = woff + x;
}

__global__ void k_scanB(int* __restrict__ partials, int* __restrict__ row_ptr,
                        int nblk) {
  int lane = threadIdx.x;
  int v = (lane < nblk) ? partials[lane] : 0;
  int x = v;
#pragma unroll
  for (int off = 1; off < 64; off <<= 1) {
    int y = __shfl_up(x, off, 64);
    if (lane >= off) x += y;
  }
  if (lane < nblk) partials[lane] = x - v;
  if (lane == 0) row_ptr[NN] = NE;
}

__global__ __launch_bounds__(256) void k_scanC(int* __restrict__ row_ptr,
                                               const int* __restrict__ partials) {
  int b = blockIdx.x;
  int off = partials[b];
  int base = b * 1024 + threadIdx.x * 4;
#pragma unroll
  for (int j = 0; j < 4; ++j)
    if (base + j < NN) row_ptr[base + j] += off;
}

__global__ __launch_bounds__(256) void k_dinv(const int* __restrict__ cnt,
                                              float* __restrict__ dinv) {
  int i = blockIdx.x * blockDim.x + threadIdx.x;
  if (i < NN) dinv[i] = rsqrtf(1.0f + (float)cnt[i]);
}

__global__ __launch_bounds__(256) void k_fill(const int* __restrict__ src,
                                              const int* __restrict__ dst,
                                              const int* __restrict__ row_ptr,
                                              int* __restrict__ cursor,
                                              int* __restrict__ col) {
  int i = blockIdx.x * blockDim.x + threadIdx.x;
  if (i < NE) {
    int d = dst[i];
    int p = atomicAdd(&cursor[d], 1);
    col[row_ptr[d] + p] = src[i];
  }
}

// ---------------- weight convert: fp32 [K][N] -> bf16 [N][K], heads fused ----
__global__ __launch_bounds__(256) void k_convw(
    const float* __restrict__ W0, const float* __restrict__ W1,
    const float* __restrict__ Wmu, const float* __restrict__ bmu,
    const float* __restrict__ Wlv, const float* __restrict__ blv,
    bf16_t* __restrict__ W0t, bf16_t* __restrict__ W1t,
    bf16_t* __restrict__ Wht, float* __restrict__ biash) {
  int k = blockIdx.x, n = threadIdx.x;
  W0t[n * 256 + k] = (bf16_t)W0[k * 256 + n];
  W1t[n * 256 + k] = (bf16_t)W1[k * 256 + n];
  float wh = (n < 128) ? Wmu[k * 128 + n] : Wlv[k * 128 + (n - 128)];
  Wht[n * 256 + k] = (bf16_t)wh;
  if (k == 0) biash[n] = (n < 128) ? bmu[n] : blv[n - 128];
}

// ---------------- MFMA GEMM, software-pipelined ----------------
// C[M x 256] = f(A) @ Bt^T ; f = optional bn(scale,shift)+relu per A-col.
// BM=BN=128, BK=64 (4 iters), 256 thr (4 waves, 2x2 of 64x64 wave-tiles).
// Register prefetch of next K-tile issued before the MFMA phase.
#define LDKP 72  // padded LDS k-stride (bf16 elems): 144 B rows -> <=2-way

__global__ __launch_bounds__(256) void k_mgemm(
    const float* __restrict__ A, const bf16_t* __restrict__ Bt,
    bf16_t* __restrict__ Cb, float* __restrict__ Cf, int M,
    const float* __restrict__ bn_scale, const float* __restrict__ bn_shift,
    const float* __restrict__ row_scale, const float* __restrict__ col_bias,
    int split) {
  __shared__ bf16_t As[128 * LDKP];
  __shared__ bf16_t Bs[128 * LDKP];
  const int tid = threadIdx.x;
  const int bm = blockIdx.x * 128;
  const int bn = blockIdx.y * 128;
  const int wave = tid >> 6, lane = tid & 63;
  const int wm = (wave >> 1) * 64, wn = (wave & 1) * 64;
  const int lm = lane & 15, lq = lane >> 4;
  const int ar = tid >> 2;         // 0..63 ; owns rows ar, ar+64
  const int akp = (tid & 3) * 16;  // k offset within BK=64 (elems)
  f32x4 acc[4][4] = {};

  float4 ra[2][4];  // A prefetch: 2 rows x 16 floats
  bf16x8 rb[2][2];  // B prefetch: 2 rows x 16 bf16

  auto loadAB = [&](int k0) {
#pragma unroll
    for (int i = 0; i < 2; ++i) {
      int grow = bm + ar + 64 * i;
      if (grow < M) {
        const float* p = &A[(size_t)grow * 256 + k0 + akp];
#pragma unroll
        for (int j = 0; j < 4; ++j) ra[i][j] = *(const float4*)(p + 4 * j);
      } else {
#pragma unroll
        for (int j = 0; j < 4; ++j) ra[i][j] = make_float4(0.f, 0.f, 0.f, 0.f);
      }
      const bf16_t* q = &Bt[(size_t)(bn + ar + 64 * i) * 256 + k0 + akp];
      rb[i][0] = *(const bf16x8*)q;
      rb[i][1] = *(const bf16x8*)(q + 8);
    }
  };

  auto stage = [&](int k0) {
    float4 sc[4], sh[4];
    if (bn_scale) {
#pragma unroll
      for (int j = 0; j < 4; ++j) {
        sc[j] = *(const float4*)&bn_scale[k0 + akp + 4 * j];
        sh[j] = *(const float4*)&bn_shift[k0 + akp + 4 * j];
      }
    }
#pragma unroll
    for (int i = 0; i < 2; ++i) {
      int r = ar + 64 * i;
      bf16_t tmp[16];
#pragma unroll
      for (int j = 0; j < 4; ++j) {
        float4 v = ra[i][j];
        if (bn_scale) {
          v.x = fmaxf(fmaf(v.x, sc[j].x, sh[j].x), 0.f);
          v.y = fmaxf(fmaf(v.y, sc[j].y, sh[j].y), 0.f);
          v.z = fmaxf(fmaf(v.z, sc[j].z, sh[j].z), 0.f);
          v.w = fmaxf(fmaf(v.w, sc[j].w, sh[j].w), 0.f);
        }
        tmp[4 * j + 0] = (bf16_t)v.x;
        tmp[4 * j + 1] = (bf16_t)v.y;
        tmp[4 * j + 2] = (bf16_t)v.z;
        tmp[4 * j + 3] = (bf16_t)v.w;
      }
      *(bf16x8*)&As[r * LDKP + akp] = *(bf16x8*)&tmp[0];
      *(bf16x8*)&As[r * LDKP + akp + 8] = *(bf16x8*)&tmp[8];
      *(bf16x8*)&Bs[r * LDKP + akp] = rb[i][0];
      *(bf16x8*)&Bs[r * LDKP + akp + 8] = rb[i][1];
    }
  };

  loadAB(0);
#pragma unroll
  for (int it = 0; it < 4; ++it) {
    stage(it * 64);
    __syncthreads();
    if (it < 3) loadAB((it + 1) * 64);  // prefetch overlaps MFMA phase
#pragma unroll
    for (int ks = 0; ks < 2; ++ks) {
      bf16x8 af[4], bfr[4];
#pragma unroll
      for (int t = 0; t < 4; ++t)
        af[t] = *(const bf16x8*)&As[(wm + t * 16 + lm) * LDKP + ks * 32 + lq * 8];
#pragma unroll
      for (int t = 0; t < 4; ++t)
        bfr[t] = *(const bf16x8*)&Bs[(wn + t * 16 + lm) * LDKP + ks * 32 + lq * 8];
#pragma unroll
      for (int i = 0; i < 4; ++i)
#pragma unroll
        for (int j = 0; j < 4; ++j)
          acc[i][j] = __builtin_amdgcn_mfma_f32_16x16x32_bf16(af[i], bfr[j],
                                                              acc[i][j], 0, 0, 0);
    }
    __syncthreads();
  }
  // epilogue: D row = wm+i*16+lq*4+r, col = wn+j*16+lm  [m89-verified layout]
#pragma unroll
  for (int i = 0; i < 4; ++i) {
#pragma unroll
    for (int r = 0; r < 4; ++r) {
      int grow = bm + wm + i * 16 + lq * 4 + r;
      if (grow >= M) continue;
      float rs = row_scale ? row_scale[grow] : 1.0f;
#pragma unroll
      for (int j = 0; j < 4; ++j) {
        int gcol = bn + wn + j * 16 + lm;
        float v = acc[i][j][r] * rs;
        if (col_bias) v += col_bias[gcol];
        if (Cb) {
          Cb[(size_t)grow * 256 + gcol] = (bf16_t)v;
        } else if (!split) {
          Cf[(size_t)grow * 256 + gcol] = v;
        } else {
          if (gcol < 128)
            Cf[(size_t)grow * 128 + gcol] = v;
          else
            Cf[(size_t)(M + grow) * 128 + (gcol - 128)] = v;
        }
      }
    }
  }
}

// ---------------- SpMM: agg[dst] = dinv[dst]*(g[dst] + sum g[src]) ---------
// g bf16 [NN][256]; half-wave per dst row (lane owns 8 feats = 16 B),
// 8-deep unrolled gathers for MLP.
__global__ __launch_bounds__(256) void k_spmm(const bf16_t* __restrict__ g,
                                              const int* __restrict__ row_ptr,
                                              const int* __restrict__ col,
                                              const float* __restrict__ dinv,
                                              float* __restrict__ out) {
  int wid = threadIdx.x >> 6, lane = threadIdx.x & 63;
  int half = lane >> 5, sl = lane & 31;
  int dst = blockIdx.x * 8 + wid * 2 + half;
  if (dst >= NN) return;
  int s = row_ptr[dst], e = row_ptr[dst + 1];
  const size_t fo = (size_t)sl * 8;
  bf16x8 sv = *(const bf16x8*)&g[(size_t)dst * 256 + fo];
  float a[8];
#pragma unroll
  for (int j = 0; j < 8; ++j) a[j] = (float)sv[j];
  for (int b0 = s; b0 < e; b0 += 32) {
    int n = e - b0;
    if (n > 32) n = 32;
    int c = (b0 + sl < e) ? col[b0 + sl] : 0;
    int i = 0;
    for (; i + 8 <= n; i += 8) {
      bf16x8 v[8];
#pragma unroll
      for (int u = 0; u < 8; ++u) {
        int sn = __shfl(c, i + u, 32);
        v[u] = *(const bf16x8*)&g[(size_t)sn * 256 + fo];
      }
#pragma unroll
      for (int u = 0; u < 8; ++u)
#pragma unroll
        for (int j = 0; j < 8; ++j) a[j] += (float)v[u][j];
    }
    for (; i < n; ++i) {
      int sn = __shfl(c, i, 32);
      bf16x8 v = *(const bf16x8*)&g[(size_t)sn * 256 + fo];
#pragma unroll
      for (int j = 0; j < 8; ++j) a[j] += (float)v[j];
    }
  }
  float dv = dinv[dst];
  float4 o0, o1;
  o0.x = a[0] * dv; o0.y = a[1] * dv; o0.z = a[2] * dv; o0.w = a[3] * dv;
  o1.x = a[4] * dv; o1.y = a[5] * dv; o1.z = a[6] * dv; o1.w = a[7] * dv;
  *(float4*)&out[(size_t)dst * 256 + fo] = o0;
  *(float4*)&out[(size_t)dst * 256 + fo + 4] = o1;
}

// ---------------- BatchNorm statistics ----------------
__global__ __launch_bounds__(256) void k_bnstats(const float* __restrict__ h,
                                                 float* __restrict__ stats) {
  int t = threadIdx.x;
  int r0 = blockIdx.x * 128;
  int r1 = r0 + 128;
  if (r1 > NN) r1 = NN;
  float s = 0.f, s2 = 0.f;
  for (int r = r0; r < r1; ++r) {
    float v = h[(size_t)r * FD + t];
    s += v;
    s2 = fmaf(v, v, s2);
  }
  atomicAdd(&stats[t], s);
  atomicAdd(&stats[FD + t], s2);
}

__global__ __launch_bounds__(256) void k_bnfinal(const float* __restrict__ stats,
                                                 const float* __restrict__ gamma,
                                                 const float* __restrict__ beta,
                                                 float* __restrict__ bnsc,
                                                 float* __restrict__ bnsh) {
  int t = threadIdx.x;
  float mean = stats[t] * (1.0f / NN);
  float var = stats[FD + t] * (1.0f / NN) - mean * mean;
  float rs = rsqrtf(var + BN_EPS);
  float sc = gamma[t] * rs;
  bnsc[t] = sc;
  bnsh[t] = beta[t] - mean * sc;
}

// ---------------- launch ----------------
extern "C" void kernel_launch(void* const* d_in, const int* in_sizes, int n_in,
                              void* d_out, int out_size, void* d_ws, size_t ws_size,
                              hipStream_t stream) {
  const float* x = (const float*)d_in[0];
  const int* ei = (const int*)d_in[1];
  const int* esrc = ei;
  const int* edst = ei + NE;
  const float* W0 = (const float*)d_in[2];
  const float* gamma0 = (const float*)d_in[4];
  const float* beta0 = (const float*)d_in[5];
  const float* W1 = (const float*)d_in[6];
  const float* gamma1 = (const float*)d_in[8];
  const float* beta1 = (const float*)d_in[9];
  const float* W_mu = (const float*)d_in[10];
  const float* b_mu = (const float*)d_in[11];
  const float* W_lv = (const float*)d_in[12];
  const float* b_lv = (const float*)d_in[13];
  float* out = (float*)d_out;

  float* agg = (float*)d_ws;                        // NN*256 fp32
  bf16_t* g16 = (bf16_t*)(agg + (size_t)NN * 256);  // NN*256 bf16
  float* dinv = (float*)(g16 + (size_t)NN * 256);   // NN
  float* stats = dinv + NN;                         // 2*FD
  float* bnsc0 = stats + 2 * FD;
  float* bnsh0 = bnsc0 + FD;
  float* bnsc1 = bnsh0 + FD;
  float* bnsh1 = bnsc1 + FD;
  float* biash = bnsh1 + FD;                        // 256
  bf16_t* W0t = (bf16_t*)(biash + 256);
  bf16_t* W1t = W0t + 256 * 256;
  bf16_t* Wht = W1t + 256 * 256;
  int* cnt = (int*)(Wht + 256 * 256);               // NN
  int* row_ptr = cnt + NN;                          // NN+4
  int* cursor = row_ptr + NN + 4;                   // NN
  int* col = cursor + NN;                           // NE
  int* partials = col + NE;                         // 64

  const int SCAN_BLKS = (NN + 1023) / 1024;  // 49

  hipMemsetAsync(cnt, 0, NN * sizeof(int), stream);
  hipMemsetAsync(cursor, 0, NN * sizeof(int), stream);
  k_count<<<(NE + 255) / 256, 256, 0, stream>>>(edst, cnt);
  k_scanA<<<SCAN_BLKS, 256, 0, stream>>>(cnt, row_ptr, partials);
  k_scanB<<<1, 64, 0, stream>>>(partials, row_ptr, SCAN_BLKS);
  k_scanC<<<SCAN_BLKS, 256, 0, stream>>>(row_ptr, partials);
  k_dinv<<<(NN + 255) / 256, 256, 0, stream>>>(cnt, dinv);
  k_fill<<<(NE + 255) / 256, 256, 0, stream>>>(esrc, edst, row_ptr, cursor, col);
  k_convw<<<256, 256, 0, stream>>>(W0, W1, W_mu, b_mu, W_lv, b_lv, W0t, W1t, Wht, biash);

  dim3 gg((NN + 127) / 128, 2);

  // layer 0: g0 = diag(dinv)*(x @ W0)
  k_mgemm<<<gg, 256, 0, stream>>>(x, W0t, g16, nullptr, NN, nullptr, nullptr,
                                  dinv, nullptr, 0);
  k_spmm<<<(NN + 7) / 8, 256, 0, stream>>>(g16, row_ptr, col, dinv, agg);
  hipMemsetAsync(stats, 0, 2 * FD * sizeof(float), stream);
  k_bnstats<<<(NN + 127) / 128, 256, 0, stream>>>(agg, stats);
  k_bnfinal<<<1, FD, 0, stream>>>(stats, gamma0, beta0, bnsc0, bnsh0);

  // layer 1: g1 = diag(dinv)*(relu(bn(agg)) @ W1)
  k_mgemm<<<gg, 256, 0, stream>>>(agg, W1t, g16, nullptr, NN, bnsc0, bnsh0,
                                  dinv, nullptr, 0);
  k_spmm<<<(NN + 7) / 8, 256, 0, stream>>>(g16, row_ptr, col, dinv, agg);
  hipMemsetAsync(stats, 0, 2 * FD * sizeof(float), stream);
  k_bnstats<<<(NN + 127) / 128, 256, 0, stream>>>(agg, stats);
  k_bnfinal<<<1, FD, 0, stream>>>(stats, gamma1, beta1, bnsc1, bnsh1);

  // heads (fused mu|logvar)
  k_mgemm<<<gg, 256, 0, stream>>>(agg, Wht, nullptr, out, NN, bnsc1, bnsh1,
                                  nullptr, biash, 1);
}

// Round 4
// 520.877 us; speedup vs baseline: 1.7367x; 1.0198x over previous
//
#include <hip/hip_runtime.h>
#include <hip/hip_bf16.h>

#define NN 50000
#define NE 800000
#define FD 256
#define LD 128
#define BN_EPS 1e-5f

typedef __bf16 bf16_t;
typedef bf16_t bf16x8 __attribute__((ext_vector_type(8)));
typedef float f32x4 __attribute__((ext_vector_type(4)));

// ---------------- CSR build ----------------

__global__ __launch_bounds__(256) void k_count(const int* __restrict__ dst,
                                               int* __restrict__ cnt) {
  int i = blockIdx.x * blockDim.x + threadIdx.x;
  if (i < NE) atomicAdd(&cnt[dst[i]], 1);
}

__global__ __launch_bounds__(256) void k_scanA(const int* __restrict__ cnt,
                                               int* __restrict__ row_ptr,
                                               int* __restrict__ partials) {
  __shared__ int ws[4];
  int b = blockIdx.x, t = threadIdx.x;
  int base = b * 1024 + t * 4;
  int vals[4];
#pragma unroll
  for (int j = 0; j < 4; ++j) vals[j] = (base + j < NN) ? cnt[base + j] : 0;
  int tsum = vals[0] + vals[1] + vals[2] + vals[3];
  int lane = t & 63, wid = t >> 6;
  int x = tsum;
#pragma unroll
  for (int off = 1; off < 64; off <<= 1) {
    int y = __shfl_up(x, off, 64);
    if (lane >= off) x += y;
  }
  if (lane == 63) ws[wid] = x;
  __syncthreads();
  int woff = 0;
  for (int w = 0; w < wid; ++w) woff += ws[w];
  int run = woff + x - tsum;
#pragma unroll
  for (int j = 0; j < 4; ++j) {
    if (base + j < NN) row_ptr[base + j] = run;
    run += vals[j];
  }
  if (t == 255) partials[b] = woff + x;
}

__global__ void k_scanB(int* __restrict__ partials, int* __restrict__ row_ptr,
                        int nblk) {
  int lane = threadIdx.x;
  int v = (lane < nblk) ? partials[lane] : 0;
  int x = v;
#pragma unroll
  for (int off = 1; off < 64; off <<= 1) {
    int y = __shfl_up(x, off, 64);
    if (lane >= off) x += y;
  }
  if (lane < nblk) partials[lane] = x - v;
  if (lane == 0) row_ptr[NN] = NE;
}

__global__ __launch_bounds__(256) void k_scanC(int* __restrict__ row_ptr,
                                               const int* __restrict__ partials) {
  int b = blockIdx.x;
  int off = partials[b];
  int base = b * 1024 + threadIdx.x * 4;
#pragma unroll
  for (int j = 0; j < 4; ++j)
    if (base + j < NN) row_ptr[base + j] += off;
}

__global__ __launch_bounds__(256) void k_dinv(const int* __restrict__ cnt,
                                              float* __restrict__ dinv) {
  int i = blockIdx.x * blockDim.x + threadIdx.x;
  if (i < NN) dinv[i] = rsqrtf(1.0f + (float)cnt[i]);
}

__global__ __launch_bounds__(256) void k_fill(const int* __restrict__ src,
                                              const int* __restrict__ dst,
                                              const int* __restrict__ row_ptr,
                                              int* __restrict__ cursor,
                                              int* __restrict__ col) {
  int i = blockIdx.x * blockDim.x + threadIdx.x;
  if (i < NE) {
    int d = dst[i];
    int p = atomicAdd(&cursor[d], 1);
    col[row_ptr[d] + p] = src[i];
  }
}

// ---------------- weight convert to MFMA-fragment-swizzled bf16 ------------
// B-fragment for (n-tile nt, k-block kb) is a 1 KB chunk: slot l (0..63) holds
// W[k = kb*32 + (l>>4)*8 + j][n = nt*16 + (l&15)], j=0..7. GEMM then reads it
// with ds_read_b128 at addr = chunk*1024 + lane*16 -> conflict-free.
__global__ __launch_bounds__(256) void k_convw(
    const float* __restrict__ W0, const float* __restrict__ W1,
    const float* __restrict__ Wmu, const float* __restrict__ bmu,
    const float* __restrict__ Wlv, const float* __restrict__ blv,
    bf16_t* __restrict__ W0s, bf16_t* __restrict__ W1s,
    bf16_t* __restrict__ Whs, float* __restrict__ biash) {
  int k = blockIdx.x, n = threadIdx.x;
  int chunk = (n >> 4) * 8 + (k >> 5);
  int slot = ((k >> 3) & 3) * 16 + (n & 15);
  int idx = chunk * 512 + slot * 8 + (k & 7);
  W0s[idx] = (bf16_t)W0[k * 256 + n];
  W1s[idx] = (bf16_t)W1[k * 256 + n];
  float wh = (n < 128) ? Wmu[k * 128 + n] : Wlv[k * 128 + (n - 128)];
  Whs[idx] = (bf16_t)wh;
  if (k == 0) biash[n] = (n < 128) ? bmu[n] : blv[n - 128];
}

// ---------------- barrier-free MFMA GEMM ----------------
// C[M x 256] = f(A) @ W ; f = optional bn(scale,shift)+relu per A-col (k).
// W pre-swizzled; block stages its 128-col half (64 chunks = 64 KB) into LDS
// once. Each wave owns a 32-row strip: A-fragments loaded DIRECTLY from
// global (16 x 16B loads, all outstanding), then 64 conflict-free ds_read_b128
// + 128 MFMA (2-way A-reuse). No K-loop barriers.
__global__ __launch_bounds__(256) void k_mgemm(
    const void* __restrict__ Ap, int a_f32, const bf16_t* __restrict__ Wswz,
    bf16_t* __restrict__ Cb, float* __restrict__ Cf, int M,
    const float* __restrict__ bn_scale, const float* __restrict__ bn_shift,
    const float* __restrict__ row_scale, const float* __restrict__ col_bias,
    int split) {
  __shared__ bf16_t Ws[64 * 512];  // 64 chunks x 1 KB
  const int tid = threadIdx.x;
  const int half = blockIdx.y;
  {
    const bf16_t* src = Wswz + (size_t)half * 64 * 512;
#pragma unroll
    for (int i = 0; i < 16; ++i) {
      int e = (i * 256 + tid) * 8;
      *(bf16x8*)&Ws[e] = *(const bf16x8*)&src[e];
    }
  }
  __syncthreads();

  const int wave = tid >> 6, lane = tid & 63;
  const int m = lane & 15, q = lane >> 4;  // A-frag: row m, k-octet q
  const int row0 = blockIdx.x * 128 + wave * 32;

  bf16x8 af[2][8];
#pragma unroll
  for (int kb = 0; kb < 8; ++kb) {
    int kbase = kb * 32 + q * 8;
    float4 s0, s1, h0, h1;
    if (bn_scale) {
      s0 = *(const float4*)&bn_scale[kbase];
      s1 = *(const float4*)&bn_scale[kbase + 4];
      h0 = *(const float4*)&bn_shift[kbase];
      h1 = *(const float4*)&bn_shift[kbase + 4];
    }
#pragma unroll
    for (int g = 0; g < 2; ++g) {
      int rg = row0 + g * 16 + m;
      int rc = rg < M ? rg : M - 1;  // clamp; garbage stays in guarded rows
      float v[8];
      if (a_f32) {
        const float* p = (const float*)Ap + (size_t)rc * 256 + kbase;
        float4 u0 = *(const float4*)p;
        float4 u1 = *(const float4*)(p + 4);
        v[0] = u0.x; v[1] = u0.y; v[2] = u0.z; v[3] = u0.w;
        v[4] = u1.x; v[5] = u1.y; v[6] = u1.z; v[7] = u1.w;
      } else {
        bf16x8 raw =
            *(const bf16x8*)((const bf16_t*)Ap + (size_t)rc * 256 + kbase);
#pragma unroll
        for (int j = 0; j < 8; ++j) v[j] = (float)raw[j];
      }
      if (bn_scale) {
        v[0] = fmaxf(fmaf(v[0], s0.x, h0.x), 0.f);
        v[1] = fmaxf(fmaf(v[1], s0.y, h0.y), 0.f);
        v[2] = fmaxf(fmaf(v[2], s0.z, h0.z), 0.f);
        v[3] = fmaxf(fmaf(v[3], s0.w, h0.w), 0.f);
        v[4] = fmaxf(fmaf(v[4], s1.x, h1.x), 0.f);
        v[5] = fmaxf(fmaf(v[5], s1.y, h1.y), 0.f);
        v[6] = fmaxf(fmaf(v[6], s1.z, h1.z), 0.f);
        v[7] = fmaxf(fmaf(v[7], s1.w, h1.w), 0.f);
      }
      bf16x8 fr;
#pragma unroll
      for (int j = 0; j < 8; ++j) fr[j] = (bf16_t)v[j];
      af[g][kb] = fr;
    }
  }

  f32x4 acc[2][8] = {};
#pragma unroll
  for (int nt = 0; nt < 8; ++nt) {
#pragma unroll
    for (int kb = 0; kb < 8; ++kb) {
      bf16x8 b = *(const bf16x8*)&Ws[(nt * 8 + kb) * 512 + lane * 8];
      acc[0][nt] = __builtin_amdgcn_mfma_f32_16x16x32_bf16(af[0][kb], b,
                                                           acc[0][nt], 0, 0, 0);
      acc[1][nt] = __builtin_amdgcn_mfma_f32_16x16x32_bf16(af[1][kb], b,
                                                           acc[1][nt], 0, 0, 0);
    }
  }

  // epilogue: D row_local = q*4 + r, col_local = m  [m89-verified layout]
#pragma unroll
  for (int g = 0; g < 2; ++g) {
#pragma unroll
    for (int r = 0; r < 4; ++r) {
      int row = row0 + g * 16 + q * 4 + r;
      if (row >= M) continue;
      float rs = row_scale ? row_scale[row] : 1.0f;
#pragma unroll
      for (int nt = 0; nt < 8; ++nt) {
        int col = half * 128 + nt * 16 + m;
        float v = acc[g][nt][r] * rs;
        if (col_bias) v += col_bias[col];
        if (Cb) {
          Cb[(size_t)row * 256 + col] = (bf16_t)v;
        } else if (!split) {
          Cf[(size_t)row * 256 + col] = v;
        } else {
          if (col < 128)
            Cf[(size_t)row * 128 + col] = v;
          else
            Cf[(size_t)(M + row) * 128 + (col - 128)] = v;
        }
      }
    }
  }
}

// ---------------- SpMM: agg[dst] = dinv[dst]*(g[dst] + sum g[src]) ---------
// g bf16 [NN][256]; half-wave per dst row (lane owns 8 feats = 16 B),
// 8-deep unrolled gathers; bf16 output.
__global__ __launch_bounds__(256) void k_spmm(const bf16_t* __restrict__ g,
                                              const int* __restrict__ row_ptr,
                                              const int* __restrict__ col,
                                              const float* __restrict__ dinv,
                                              bf16_t* __restrict__ out) {
  int wid = threadIdx.x >> 6, lane = threadIdx.x & 63;
  int half = lane >> 5, sl = lane & 31;
  int dst = blockIdx.x * 8 + wid * 2 + half;
  if (dst >= NN) return;
  int s = row_ptr[dst], e = row_ptr[dst + 1];
  const size_t fo = (size_t)sl * 8;
  bf16x8 sv = *(const bf16x8*)&g[(size_t)dst * 256 + fo];
  float a[8];
#pragma unroll
  for (int j = 0; j < 8; ++j) a[j] = (float)sv[j];
  for (int b0 = s; b0 < e; b0 += 32) {
    int n = e - b0;
    if (n > 32) n = 32;
    int c = (b0 + sl < e) ? col[b0 + sl] : 0;
    int i = 0;
    for (; i + 8 <= n; i += 8) {
      bf16x8 v[8];
#pragma unroll
      for (int u = 0; u < 8; ++u) {
        int sn = __shfl(c, i + u, 32);
        v[u] = *(const bf16x8*)&g[(size_t)sn * 256 + fo];
      }
#pragma unroll
      for (int u = 0; u < 8; ++u)
#pragma unroll
        for (int j = 0; j < 8; ++j) a[j] += (float)v[u][j];
    }
    for (; i < n; ++i) {
      int sn = __shfl(c, i, 32);
      bf16x8 v = *(const bf16x8*)&g[(size_t)sn * 256 + fo];
#pragma unroll
      for (int j = 0; j < 8; ++j) a[j] += (float)v[j];
    }
  }
  float dv = dinv[dst];
  bf16x8 ov;
#pragma unroll
  for (int j = 0; j < 8; ++j) ov[j] = (bf16_t)(a[j] * dv);
  *(bf16x8*)&out[(size_t)dst * 256 + fo] = ov;
}

// ---------------- BatchNorm statistics (bf16 input) ----------------
__global__ __launch_bounds__(256) void k_bnstats(const bf16_t* __restrict__ h,
                                                 float* __restrict__ stats) {
  int t = threadIdx.x;
  int r0 = blockIdx.x * 128;
  int r1 = r0 + 128;
  if (r1 > NN) r1 = NN;
  float s = 0.f, s2 = 0.f;
  for (int r = r0; r < r1; ++r) {
    float v = (float)h[(size_t)r * FD + t];
    s += v;
    s2 = fmaf(v, v, s2);
  }
  atomicAdd(&stats[t], s);
  atomicAdd(&stats[FD + t], s2);
}

__global__ __launch_bounds__(256) void k_bnfinal(const float* __restrict__ stats,
                                                 const float* __restrict__ gamma,
                                                 const float* __restrict__ beta,
                                                 float* __restrict__ bnsc,
                                                 float* __restrict__ bnsh) {
  int t = threadIdx.x;
  float mean = stats[t] * (1.0f / NN);
  float var = stats[FD + t] * (1.0f / NN) - mean * mean;
  float rs = rsqrtf(var + BN_EPS);
  float sc = gamma[t] * rs;
  bnsc[t] = sc;
  bnsh[t] = beta[t] - mean * sc;
}

// ---------------- launch ----------------
extern "C" void kernel_launch(void* const* d_in, const int* in_sizes, int n_in,
                              void* d_out, int out_size, void* d_ws, size_t ws_size,
                              hipStream_t stream) {
  const float* x = (const float*)d_in[0];
  const int* ei = (const int*)d_in[1];
  const int* esrc = ei;
  const int* edst = ei + NE;
  const float* W0 = (const float*)d_in[2];
  const float* gamma0 = (const float*)d_in[4];
  const float* beta0 = (const float*)d_in[5];
  const float* W1 = (const float*)d_in[6];
  const float* gamma1 = (const float*)d_in[8];
  const float* beta1 = (const float*)d_in[9];
  const float* W_mu = (const float*)d_in[10];
  const float* b_mu = (const float*)d_in[11];
  const float* W_lv = (const float*)d_in[12];
  const float* b_lv = (const float*)d_in[13];
  float* out = (float*)d_out;

  // workspace carve
  bf16_t* g16 = (bf16_t*)d_ws;                       // NN*256 bf16
  bf16_t* agg16 = g16 + (size_t)NN * 256;            // NN*256 bf16
  float* dinv = (float*)(agg16 + (size_t)NN * 256);  // NN
  float* stats = dinv + NN;                          // 2*FD
  float* bnsc0 = stats + 2 * FD;
  float* bnsh0 = bnsc0 + FD;
  float* bnsc1 = bnsh0 + FD;
  float* bnsh1 = bnsc1 + FD;
  float* biash = bnsh1 + FD;                         // 256
  bf16_t* W0s = (bf16_t*)(biash + 256);              // 65536 bf16 each
  bf16_t* W1s = W0s + 256 * 256;
  bf16_t* Whs = W1s + 256 * 256;
  int* cnt = (int*)(Whs + 256 * 256);                // NN
  int* row_ptr = cnt + NN;                           // NN+4
  int* cursor = row_ptr + NN + 4;                    // NN
  int* col = cursor + NN;                            // NE
  int* partials = col + NE;                          // 64

  const int SCAN_BLKS = (NN + 1023) / 1024;  // 49

  hipMemsetAsync(cnt, 0, NN * sizeof(int), stream);
  hipMemsetAsync(cursor, 0, NN * sizeof(int), stream);
  k_count<<<(NE + 255) / 256, 256, 0, stream>>>(edst, cnt);
  k_scanA<<<SCAN_BLKS, 256, 0, stream>>>(cnt, row_ptr, partials);
  k_scanB<<<1, 64, 0, stream>>>(partials, row_ptr, SCAN_BLKS);
  k_scanC<<<SCAN_BLKS, 256, 0, stream>>>(row_ptr, partials);
  k_dinv<<<(NN + 255) / 256, 256, 0, stream>>>(cnt, dinv);
  k_fill<<<(NE + 255) / 256, 256, 0, stream>>>(esrc, edst, row_ptr, cursor, col);
  k_convw<<<256, 256, 0, stream>>>(W0, W1, W_mu, b_mu, W_lv, b_lv, W0s, W1s,
                                   Whs, biash);

  dim3 gg((NN + 127) / 128, 2);

  // layer 0: g0 = diag(dinv)*(x @ W0)   [fp32 A, no BN]
  k_mgemm<<<gg, 256, 0, stream>>>(x, 1, W0s, g16, nullptr, NN, nullptr, nullptr,
                                  dinv, nullptr, 0);
  k_spmm<<<(NN + 7) / 8, 256, 0, stream>>>(g16, row_ptr, col, dinv, agg16);
  hipMemsetAsync(stats, 0, 2 * FD * sizeof(float), stream);
  k_bnstats<<<(NN + 127) / 128, 256, 0, stream>>>(agg16, stats);
  k_bnfinal<<<1, FD, 0, stream>>>(stats, gamma0, beta0, bnsc0, bnsh0);

  // layer 1: g1 = diag(dinv)*(relu(bn(agg)) @ W1)   [bf16 A + in-reg BN]
  k_mgemm<<<gg, 256, 0, stream>>>(agg16, 0, W1s, g16, nullptr, NN, bnsc0, bnsh0,
                                  dinv, nullptr, 0);
  k_spmm<<<(NN + 7) / 8, 256, 0, stream>>>(g16, row_ptr, col, dinv, agg16);
  hipMemsetAsync(stats, 0, 2 * FD * sizeof(float), stream);
  k_bnstats<<<(NN + 127) / 128, 256, 0, stream>>>(agg16, stats);
  k_bnfinal<<<1, FD, 0, stream>>>(stats, gamma1, beta1, bnsc1, bnsh1);

  // heads (fused mu|logvar): out = relu(bn(agg)) @ [W_mu|W_lv] + bias
  k_mgemm<<<gg, 256, 0, stream>>>(agg16, 0, Whs, nullptr, out, NN, bnsc1, bnsh1,
                                  nullptr, biash, 1);
}

// Round 5
// 485.406 us; speedup vs baseline: 1.8636x; 1.0731x over previous
//
#include <hip/hip_runtime.h>
#include <hip/hip_bf16.h>

#define NN 50000
#define NE 800000
#define FD 256
#define LD 128
#define BN_EPS 1e-5f

typedef __bf16 bf16_t;
typedef bf16_t bf16x8 __attribute__((ext_vector_type(8)));
typedef float f32x4 __attribute__((ext_vector_type(4)));

// ---------------- CSR build ----------------

__global__ __launch_bounds__(256) void k_count(const int* __restrict__ dst,
                                               int* __restrict__ cnt) {
  int i = blockIdx.x * blockDim.x + threadIdx.x;
  if (i < NE) atomicAdd(&cnt[dst[i]], 1);
}

__global__ __launch_bounds__(256) void k_scanA(const int* __restrict__ cnt,
                                               int* __restrict__ row_ptr,
                                               int* __restrict__ partials) {
  __shared__ int ws[4];
  int b = blockIdx.x, t = threadIdx.x;
  int base = b * 1024 + t * 4;
  int vals[4];
#pragma unroll
  for (int j = 0; j < 4; ++j) vals[j] = (base + j < NN) ? cnt[base + j] : 0;
  int tsum = vals[0] + vals[1] + vals[2] + vals[3];
  int lane = t & 63, wid = t >> 6;
  int x = tsum;
#pragma unroll
  for (int off = 1; off < 64; off <<= 1) {
    int y = __shfl_up(x, off, 64);
    if (lane >= off) x += y;
  }
  if (lane == 63) ws[wid] = x;
  __syncthreads();
  int woff = 0;
  for (int w = 0; w < wid; ++w) woff += ws[w];
  int run = woff + x - tsum;
#pragma unroll
  for (int j = 0; j < 4; ++j) {
    if (base + j < NN) row_ptr[base + j] = run;
    run += vals[j];
  }
  if (t == 255) partials[b] = woff + x;
}

__global__ void k_scanB(int* __restrict__ partials, int* __restrict__ row_ptr,
                        int nblk) {
  int lane = threadIdx.x;
  int v = (lane < nblk) ? partials[lane] : 0;
  int x = v;
#pragma unroll
  for (int off = 1; off < 64; off <<= 1) {
    int y = __shfl_up(x, off, 64);
    if (lane >= off) x += y;
  }
  if (lane < nblk) partials[lane] = x - v;
  if (lane == 0) row_ptr[NN] = NE;
}

// scanC + dinv fused
__global__ __launch_bounds__(256) void k_scanC(int* __restrict__ row_ptr,
                                               const int* __restrict__ partials,
                                               const int* __restrict__ cnt,
                                               float* __restrict__ dinv) {
  int b = blockIdx.x;
  int off = partials[b];
  int base = b * 1024 + threadIdx.x * 4;
#pragma unroll
  for (int j = 0; j < 4; ++j)
    if (base + j < NN) {
      row_ptr[base + j] += off;
      dinv[base + j] = rsqrtf(1.0f + (float)cnt[base + j]);
    }
}

__global__ __launch_bounds__(256) void k_fill(const int* __restrict__ src,
                                              const int* __restrict__ dst,
                                              const int* __restrict__ row_ptr,
                                              int* __restrict__ cursor,
                                              int* __restrict__ col) {
  int i = blockIdx.x * blockDim.x + threadIdx.x;
  if (i < NE) {
    int d = dst[i];
    int p = atomicAdd(&cursor[d], 1);
    col[row_ptr[d] + p] = src[i];
  }
}

// ---------------- weight convert to MFMA-fragment-swizzled bf16 ------------
__global__ __launch_bounds__(256) void k_convw(
    const float* __restrict__ W0, const float* __restrict__ W1,
    const float* __restrict__ Wmu, const float* __restrict__ bmu,
    const float* __restrict__ Wlv, const float* __restrict__ blv,
    bf16_t* __restrict__ W0s, bf16_t* __restrict__ W1s,
    bf16_t* __restrict__ Whs, float* __restrict__ biash) {
  int k = blockIdx.x, n = threadIdx.x;
  int chunk = (n >> 4) * 8 + (k >> 5);
  int slot = ((k >> 3) & 3) * 16 + (n & 15);
  int idx = chunk * 512 + slot * 8 + (k & 7);
  W0s[idx] = (bf16_t)W0[k * 256 + n];
  W1s[idx] = (bf16_t)W1[k * 256 + n];
  float wh = (n < 128) ? Wmu[k * 128 + n] : Wlv[k * 128 + (n - 128)];
  Whs[idx] = (bf16_t)wh;
  if (k == 0) biash[n] = (n < 128) ? bmu[n] : blv[n - 128];
}

// ---------------- barrier-free MFMA GEMM, batched raw loads ----------------
__global__ __launch_bounds__(256) void k_mgemm(
    const void* __restrict__ Ap, int a_f32, const bf16_t* __restrict__ Wswz,
    bf16_t* __restrict__ Cb, float* __restrict__ Cf, int M,
    const float* __restrict__ bn_scale, const float* __restrict__ bn_shift,
    const float* __restrict__ row_scale, const float* __restrict__ col_bias,
    int split) {
  __shared__ bf16_t Ws[64 * 512];  // 64 chunks x 1 KB
  const int tid = threadIdx.x;
  const int half = blockIdx.y;
  {
    const bf16_t* srcW = Wswz + (size_t)half * 64 * 512;
    bf16x8 wraw[16];
#pragma unroll
    for (int i = 0; i < 16; ++i)
      wraw[i] = *(const bf16x8*)&srcW[(i * 256 + tid) * 8];
#pragma unroll
    for (int i = 0; i < 16; ++i) *(bf16x8*)&Ws[(i * 256 + tid) * 8] = wraw[i];
  }
  __syncthreads();

  const int wave = tid >> 6, lane = tid & 63;
  const int m = lane & 15, q = lane >> 4;  // A-frag: row m, k-octet q
  const int row0 = blockIdx.x * 128 + wave * 32;
  const int rg0 = row0 + m, rg1 = row0 + 16 + m;
  const int rc0 = rg0 < M ? rg0 : M - 1;
  const int rc1 = rg1 < M ? rg1 : M - 1;

  bf16x8 af[2][8];
  if (a_f32) {
    const float* p0 = (const float*)Ap + (size_t)rc0 * 256 + q * 8;
    const float* p1 = (const float*)Ap + (size_t)rc1 * 256 + q * 8;
#pragma unroll
    for (int g = 0; g < 2; ++g) {
      const float* p = g ? p1 : p0;
      float4 f0[8], f1[8];
#pragma unroll
      for (int kb = 0; kb < 8; ++kb) {
        f0[kb] = *(const float4*)(p + kb * 32);
        f1[kb] = *(const float4*)(p + kb * 32 + 4);
      }
#pragma unroll
      for (int kb = 0; kb < 8; ++kb) {
        bf16x8 fr;
        fr[0] = (bf16_t)f0[kb].x; fr[1] = (bf16_t)f0[kb].y;
        fr[2] = (bf16_t)f0[kb].z; fr[3] = (bf16_t)f0[kb].w;
        fr[4] = (bf16_t)f1[kb].x; fr[5] = (bf16_t)f1[kb].y;
        fr[6] = (bf16_t)f1[kb].z; fr[7] = (bf16_t)f1[kb].w;
        af[g][kb] = fr;
      }
    }
  } else {
    const bf16_t* p0 = (const bf16_t*)Ap + (size_t)rc0 * 256 + q * 8;
    const bf16_t* p1 = (const bf16_t*)Ap + (size_t)rc1 * 256 + q * 8;
    bf16x8 raw[16];
#pragma unroll
    for (int kb = 0; kb < 8; ++kb) {
      raw[kb * 2 + 0] = *(const bf16x8*)(p0 + kb * 32);
      raw[kb * 2 + 1] = *(const bf16x8*)(p1 + kb * 32);
    }
#pragma unroll
    for (int kb = 0; kb < 8; ++kb) {
      float s[8], h[8];
      if (bn_scale) {
        float4 s0 = *(const float4*)&bn_scale[kb * 32 + q * 8];
        float4 s1 = *(const float4*)&bn_scale[kb * 32 + q * 8 + 4];
        float4 h0 = *(const float4*)&bn_shift[kb * 32 + q * 8];
        float4 h1 = *(const float4*)&bn_shift[kb * 32 + q * 8 + 4];
        s[0] = s0.x; s[1] = s0.y; s[2] = s0.z; s[3] = s0.w;
        s[4] = s1.x; s[5] = s1.y; s[6] = s1.z; s[7] = s1.w;
        h[0] = h0.x; h[1] = h0.y; h[2] = h0.z; h[3] = h0.w;
        h[4] = h1.x; h[5] = h1.y; h[6] = h1.z; h[7] = h1.w;
      }
#pragma unroll
      for (int g = 0; g < 2; ++g) {
        bf16x8 r = raw[kb * 2 + g];
        bf16x8 fr;
#pragma unroll
        for (int j = 0; j < 8; ++j) {
          float v = (float)r[j];
          if (bn_scale) v = fmaxf(fmaf(v, s[j], h[j]), 0.f);
          fr[j] = (bf16_t)v;
        }
        af[g][kb] = fr;
      }
    }
  }

  f32x4 acc[2][8] = {};
#pragma unroll
  for (int nt = 0; nt < 8; ++nt) {
#pragma unroll
    for (int kb = 0; kb < 8; ++kb) {
      bf16x8 b = *(const bf16x8*)&Ws[(nt * 8 + kb) * 512 + lane * 8];
      acc[0][nt] = __builtin_amdgcn_mfma_f32_16x16x32_bf16(af[0][kb], b,
                                                           acc[0][nt], 0, 0, 0);
      acc[1][nt] = __builtin_amdgcn_mfma_f32_16x16x32_bf16(af[1][kb], b,
                                                           acc[1][nt], 0, 0, 0);
    }
  }

  // epilogue: D row_local = q*4 + r, col_local = m  [m89-verified layout]
#pragma unroll
  for (int g = 0; g < 2; ++g) {
#pragma unroll
    for (int r = 0; r < 4; ++r) {
      int row = row0 + g * 16 + q * 4 + r;
      if (row >= M) continue;
      float rs = row_scale ? row_scale[row] : 1.0f;
#pragma unroll
      for (int nt = 0; nt < 8; ++nt) {
        int col = half * 128 + nt * 16 + m;
        float v = acc[g][nt][r] * rs;
        if (col_bias) v += col_bias[col];
        if (Cb) {
          Cb[(size_t)row * 256 + col] = (bf16_t)v;
        } else if (!split) {
          Cf[(size_t)row * 256 + col] = v;
        } else {
          if (col < 128)
            Cf[(size_t)row * 128 + col] = v;
          else
            Cf[(size_t)(M + row) * 128 + (col - 128)] = v;
        }
      }
    }
  }
}

// ---------------- SpMM + fused BN stats ----------------
// agg[dst] = dinv[dst]*(g[dst] + sum g[src]); also accumulates sum / sumsq of
// the bf16-rounded output into stats[0..255] / stats[256..511].
// Half-wave (32 lanes) per row, lane owns 8 feats (16 B); 4 rows/half-wave;
// 16-deep gather pipeline.
__global__ __launch_bounds__(256) void k_spmm(const bf16_t* __restrict__ g,
                                              const int* __restrict__ row_ptr,
                                              const int* __restrict__ col,
                                              const float* __restrict__ dinv,
                                              bf16_t* __restrict__ out,
                                              float* __restrict__ stats) {
  __shared__ float sbuf[8][256];
  int hw = threadIdx.x >> 5, sl = threadIdx.x & 31;
  const size_t fo = (size_t)sl * 8;
  float s[8] = {}, s2[8] = {};
#pragma unroll 1
  for (int jr = 0; jr < 4; ++jr) {
    int dst = blockIdx.x * 32 + hw * 4 + jr;
    if (dst >= NN) break;
    int sidx = row_ptr[dst], e = row_ptr[dst + 1];
    bf16x8 sv = *(const bf16x8*)&g[(size_t)dst * 256 + fo];
    float a[8];
#pragma unroll
    for (int j = 0; j < 8; ++j) a[j] = (float)sv[j];
    for (int b0 = sidx; b0 < e; b0 += 32) {
      int n = e - b0;
      if (n > 32) n = 32;
      int c = (b0 + sl < e) ? col[b0 + sl] : 0;
      int i = 0;
      for (; i + 16 <= n; i += 16) {
        bf16x8 v[16];
#pragma unroll
        for (int u = 0; u < 16; ++u) {
          int sn = __shfl(c, i + u, 32);
          v[u] = *(const bf16x8*)&g[(size_t)sn * 256 + fo];
        }
#pragma unroll
        for (int u = 0; u < 16; ++u)
#pragma unroll
          for (int j = 0; j < 8; ++j) a[j] += (float)v[u][j];
      }
      for (; i + 4 <= n; i += 4) {
        bf16x8 v[4];
#pragma unroll
        for (int u = 0; u < 4; ++u) {
          int sn = __shfl(c, i + u, 32);
          v[u] = *(const bf16x8*)&g[(size_t)sn * 256 + fo];
        }
#pragma unroll
        for (int u = 0; u < 4; ++u)
#pragma unroll
          for (int j = 0; j < 8; ++j) a[j] += (float)v[u][j];
      }
      for (; i < n; ++i) {
        int sn = __shfl(c, i, 32);
        bf16x8 v = *(const bf16x8*)&g[(size_t)sn * 256 + fo];
#pragma unroll
        for (int j = 0; j < 8; ++j) a[j] += (float)v[j];
      }
    }
    float dv = dinv[dst];
    bf16x8 ov;
#pragma unroll
    for (int j = 0; j < 8; ++j) ov[j] = (bf16_t)(a[j] * dv);
    *(bf16x8*)&out[(size_t)dst * 256 + fo] = ov;
#pragma unroll
    for (int j = 0; j < 8; ++j) {
      float vq = (float)ov[j];
      s[j] += vq;
      s2[j] = fmaf(vq, vq, s2[j]);
    }
  }
  // block reduction of stats
#pragma unroll
  for (int j = 0; j < 8; ++j) sbuf[hw][sl * 8 + j] = s[j];
  __syncthreads();
  {
    int t = threadIdx.x;
    float tot = 0.f;
#pragma unroll
    for (int w = 0; w < 8; ++w) tot += sbuf[w][t];
    atomicAdd(&stats[t], tot);
  }
  __syncthreads();
#pragma unroll
  for (int j = 0; j < 8; ++j) sbuf[hw][sl * 8 + j] = s2[j];
  __syncthreads();
  {
    int t = threadIdx.x;
    float tot = 0.f;
#pragma unroll
    for (int w = 0; w < 8; ++w) tot += sbuf[w][t];
    atomicAdd(&stats[256 + t], tot);
  }
}

__global__ __launch_bounds__(256) void k_bnfinal(const float* __restrict__ stats,
                                                 const float* __restrict__ gamma,
                                                 const float* __restrict__ beta,
                                                 float* __restrict__ bnsc,
                                                 float* __restrict__ bnsh) {
  int t = threadIdx.x;
  float mean = stats[t] * (1.0f / NN);
  float var = stats[256 + t] * (1.0f / NN) - mean * mean;
  float rs = rsqrtf(var + BN_EPS);
  float sc = gamma[t] * rs;
  bnsc[t] = sc;
  bnsh[t] = beta[t] - mean * sc;
}

// ---------------- launch ----------------
extern "C" void kernel_launch(void* const* d_in, const int* in_sizes, int n_in,
                              void* d_out, int out_size, void* d_ws, size_t ws_size,
                              hipStream_t stream) {
  const float* x = (const float*)d_in[0];
  const int* ei = (const int*)d_in[1];
  const int* esrc = ei;
  const int* edst = ei + NE;
  const float* W0 = (const float*)d_in[2];
  const float* gamma0 = (const float*)d_in[4];
  const float* beta0 = (const float*)d_in[5];
  const float* W1 = (const float*)d_in[6];
  const float* gamma1 = (const float*)d_in[8];
  const float* beta1 = (const float*)d_in[9];
  const float* W_mu = (const float*)d_in[10];
  const float* b_mu = (const float*)d_in[11];
  const float* W_lv = (const float*)d_in[12];
  const float* b_lv = (const float*)d_in[13];
  float* out = (float*)d_out;

  // workspace carve: cnt|cursor|statsAll contiguous -> one memset
  bf16_t* g16 = (bf16_t*)d_ws;                        // NN*256
  bf16_t* agg16 = g16 + (size_t)NN * 256;             // NN*256
  int* cnt = (int*)(agg16 + (size_t)NN * 256);        // NN
  int* cursor = cnt + NN;                             // NN
  float* statsAll = (float*)(cursor + NN);            // 1024 (2 layers x 512)
  float* dinv = statsAll + 1024;                      // NN
  float* bnsc0 = dinv + NN;
  float* bnsh0 = bnsc0 + FD;
  float* bnsc1 = bnsh0 + FD;
  float* bnsh1 = bnsc1 + FD;
  float* biash = bnsh1 + FD;                          // 256
  bf16_t* W0s = (bf16_t*)(biash + 256);               // 65536 each
  bf16_t* W1s = W0s + 256 * 256;
  bf16_t* Whs = W1s + 256 * 256;
  int* row_ptr = (int*)(Whs + 256 * 256);             // NN+4
  int* col = row_ptr + NN + 4;                        // NE
  int* partials = col + NE;                           // 64

  const int SCAN_BLKS = (NN + 1023) / 1024;  // 49

  hipMemsetAsync(cnt, 0, (2 * NN + 1024) * sizeof(int), stream);
  k_count<<<(NE + 255) / 256, 256, 0, stream>>>(edst, cnt);
  k_scanA<<<SCAN_BLKS, 256, 0, stream>>>(cnt, row_ptr, partials);
  k_scanB<<<1, 64, 0, stream>>>(partials, row_ptr, SCAN_BLKS);
  k_scanC<<<SCAN_BLKS, 256, 0, stream>>>(row_ptr, partials, cnt, dinv);
  k_fill<<<(NE + 255) / 256, 256, 0, stream>>>(esrc, edst, row_ptr, cursor, col);
  k_convw<<<256, 256, 0, stream>>>(W0, W1, W_mu, b_mu, W_lv, b_lv, W0s, W1s,
                                   Whs, biash);

  dim3 gg((NN + 127) / 128, 2);
  const int SPMM_BLKS = (NN + 31) / 32;  // 1563

  // layer 0
  k_mgemm<<<gg, 256, 0, stream>>>(x, 1, W0s, g16, nullptr, NN, nullptr, nullptr,
                                  dinv, nullptr, 0);
  k_spmm<<<SPMM_BLKS, 256, 0, stream>>>(g16, row_ptr, col, dinv, agg16, statsAll);
  k_bnfinal<<<1, FD, 0, stream>>>(statsAll, gamma0, beta0, bnsc0, bnsh0);

  // layer 1
  k_mgemm<<<gg, 256, 0, stream>>>(agg16, 0, W1s, g16, nullptr, NN, bnsc0, bnsh0,
                                  dinv, nullptr, 0);
  k_spmm<<<SPMM_BLKS, 256, 0, stream>>>(g16, row_ptr, col, dinv, agg16,
                                        statsAll + 512);
  k_bnfinal<<<1, FD, 0, stream>>>(statsAll + 512, gamma1, beta1, bnsc1, bnsh1);

  // heads (fused mu|logvar)
  k_mgemm<<<gg, 256, 0, stream>>>(agg16, 0, Whs, nullptr, out, NN, bnsc1, bnsh1,
                                  nullptr, biash, 1);
}